// Round 5
// baseline (837.798 us; speedup 1.0000x reference)
//
#include <hip/hip_runtime.h>
#include <hip/hip_cooperative_groups.h>
#include <stdint.h>

namespace cg = cooperative_groups;

#define RES      512
#define TEXELS   (RES * RES)          // 262144
#define NPTS     1000000
#define RANK     48
#define ODIM     32
#define PPB      64                   // points per block (geo_main)
#define VMS      52                   // vm LDS row stride (floats), pad 48->52
#define OSTR     33                   // out-staging LDS row stride
#define TT       128                  // texels per transpose tile
#define TS       25                   // LDS row stride (dwords), coprime w/ 32
#define NCELL    4096                 // 16x16x16 Morton cells
#define NB       64                   // binning segments (NPTS/NB = 15625 exact)
#define SEG      15625
#define NTILE    6144                 // plane-transpose tiles (2048 * 3)
#define NBLK     1024                 // cooperative grid (4 blocks/CU on 256 CUs)

typedef unsigned int u32;
typedef float vf4 __attribute__((ext_vector_type(4)));

__device__ __forceinline__ float lobf(u32 u) { return __uint_as_float(u << 16); }
__device__ __forceinline__ float hibf(u32 u) { return __uint_as_float(u & 0xffff0000u); }

__device__ __forceinline__ float ntl(const float* p) {
    return __builtin_nontemporal_load(p);
}
__device__ __forceinline__ vf4 ntl4(const float* p) {
    return __builtin_nontemporal_load((const vf4*)p);
}

// RNE pack two fp32 -> bf16x2 (a low, b high)
__device__ __forceinline__ u32 pkbf(float a, float b) {
    u32 x = __float_as_uint(a), y = __float_as_uint(b);
    u32 xr = (x + 0x7fffu + ((x >> 16) & 1u)) >> 16;
    u32 yr = (y + 0x7fffu + ((y >> 16) & 1u)) & 0xffff0000u;
    return xr | yr;
}

// ---------- Morton cell id, 16^3 (identical in count & scatter) -------------
__device__ __forceinline__ u32 sprd4(u32 a) {
    a &= 15u;
    a = (a | (a << 4)) & 0x0C3u;
    a = (a | (a << 2)) & 0x249u;
    return a;
}
__device__ __forceinline__ u32 cellOf(float x, float y, float z) {
    u32 cx = (u32)fminf(fmaxf(x * 16.f, 0.f), 15.f);
    u32 cy = (u32)fminf(fmaxf(y * 16.f, 0.f), 15.f);
    u32 cz = (u32)fminf(fmaxf(z * 16.f, 0.f), 15.f);
    return sprd4(cx) | (sprd4(cy) << 1) | (sprd4(cz) << 2);   // < 4096
}

// ============================ ROLE FUNCTIONS =================================
// Shared LDS buffer: u32 smem[NCELL + 8] (16.03 KB). tp uses 3208, hist/cur 4096.

// plane-transpose one tile (TEXB=96): tile in [0, NTILE)
__device__ __forceinline__ void tp_role(int tile, int t,
    const float* __restrict__ p0, const float* __restrict__ p1,
    const float* __restrict__ p2, char* __restrict__ ws, u32* lds)
{
    int tno = tile & 2047;
    int plane = tile >> 11;
    const float* src = (plane == 0) ? p0 : ((plane == 1) ? p1 : p2);
    int base = tno * TT;
    int xi = t & 31, dg = t >> 5;
#pragma unroll
    for (int j = 0; j < 3; ++j) {
        int d = dg + 8 * j;                         // dword 0..23 (ch 2d,2d+1)
        vf4 a = ntl4(src + (size_t)(2 * d) * TEXELS + base + 4 * xi);
        vf4 b = ntl4(src + (size_t)(2 * d + 1) * TEXELS + base + 4 * xi);
        lds[(4 * xi + 0) * TS + d] = pkbf(a.x, b.x);
        lds[(4 * xi + 1) * TS + d] = pkbf(a.y, b.y);
        lds[(4 * xi + 2) * TS + d] = pkbf(a.z, b.z);
        lds[(4 * xi + 3) * TS + d] = pkbf(a.w, b.w);
    }
    __syncthreads();
    char* outp = ws + (size_t)plane * TEXELS * 96 + (size_t)base * 96;
#pragma unroll
    for (int s = 0; s < 3; ++s) {                   // 128*96/(16*256) = 3 stores
        u32 o = (u32)(s * 256 + t) * 16u;
        u32 texel = ((o >> 5) * 43691u) >> 17;      // o/96
        u32 rem = o - texel * 96u;
        u32 dw = texel * TS + (rem >> 2);
        uint4 q = make_uint4(lds[dw], lds[dw + 1], lds[dw + 2], lds[dw + 3]);
        *(uint4*)(outp + o) = q;
    }
    __syncthreads();                                // lds reused by next tile
}

// run a strided range of tp tiles: worker w of nw covers [lo, hi)
__device__ __forceinline__ void tp_range(int lo, int hi, int w, int nw, int t,
    const float* p0, const float* p1, const float* p2, char* ws, u32* lds)
{
    for (int tile = lo + w; tile < hi; tile += nw)
        tp_role(tile, t, p0, p1, p2, ws, lds);
}

// line transpose job j in [0,6)
__device__ __forceinline__ void lines_role(int j, int t,
    const float* __restrict__ lz, const float* __restrict__ ly,
    const float* __restrict__ lx, char* __restrict__ ws)
{
    int id = j * 256 + t;
    int line = id >> 9;
    int pos = id & (RES - 1);
    const float* src = (line == 0) ? lz : ((line == 1) ? ly : lx);
    char* dst = ws + (size_t)3 * TEXELS * 96 + (size_t)line * RES * 96
                   + (size_t)pos * 96;
#pragma unroll
    for (int k = 0; k < 6; ++k) {
        uint4 q;
        q.x = pkbf(ntl(&src[(8 * k + 0) * RES + pos]), ntl(&src[(8 * k + 1) * RES + pos]));
        q.y = pkbf(ntl(&src[(8 * k + 2) * RES + pos]), ntl(&src[(8 * k + 3) * RES + pos]));
        q.z = pkbf(ntl(&src[(8 * k + 4) * RES + pos]), ntl(&src[(8 * k + 5) * RES + pos]));
        q.w = pkbf(ntl(&src[(8 * k + 6) * RES + pos]), ntl(&src[(8 * k + 7) * RES + pos]));
        *(uint4*)(dst + 16 * k) = q;
    }
}

// count segment blk: LDS histogram -> T[cell][NB]
__device__ __forceinline__ void count_role(int blk, int t,
    const float* __restrict__ coords, u32* __restrict__ T, u32* hist)
{
#pragma unroll
    for (int i = 0; i < NCELL / 256; ++i) hist[t + 256 * i] = 0u;
    __syncthreads();
    int lim = (blk + 1) * SEG;
#pragma unroll 1
    for (int it = 0; it < (SEG + 255) / 256; ++it) {
        int idx = blk * SEG + it * 256 + t;
        if (idx < lim) {
            float x = ntl(&coords[3 * idx + 0]);
            float y = ntl(&coords[3 * idx + 1]);
            float z = ntl(&coords[3 * idx + 2]);
            atomicAdd(&hist[cellOf(x, y, z)], 1u);  // LDS atomic
        }
    }
    __syncthreads();
#pragma unroll
    for (int i = 0; i < NCELL / 256; ++i) {
        int cell = t + 256 * i;
        T[(u32)cell * NB + blk] = hist[cell];
    }
}

// within-cell exclusive prefix (in place), 16 blocks x 256 threads, 1 cell/thread
__device__ __forceinline__ void prefix_role(int bid, int t,
    u32* __restrict__ T, u32* __restrict__ cellTot)
{
    int cell = bid * 256 + t;                       // < 4096
    u32* tp = T + (u32)cell * NB;
    u32 run = 0;
#pragma unroll 8
    for (int b = 0; b < NB; ++b) { u32 v = tp[b]; tp[b] = run; run += v; }
    cellTot[cell] = run;
}

// exclusive scan of cellTot[4096] -> cellBase, 1 block x 256 threads
__device__ __forceinline__ void base_role(int t,
    const u32* __restrict__ cellTot, u32* __restrict__ cellBase, u32* wt)
{
    u32 loc[16];
    u32 s = 0;
#pragma unroll
    for (int i = 0; i < 16; ++i) { loc[i] = s; s += cellTot[t * 16 + i]; }
    u32 tot = s;
    int lane = t & 63, w = t >> 6;
    u32 incl = tot;
#pragma unroll
    for (int d = 1; d < 64; d <<= 1) {
        u32 v = __shfl_up(incl, d);
        if (lane >= d) incl += v;
    }
    if (lane == 63) wt[w] = incl;
    __syncthreads();
    u32 base = incl - tot;
#pragma unroll
    for (int i = 0; i < 4; ++i) base += (i < w) ? wt[i] : 0u;
#pragma unroll
    for (int i = 0; i < 16; ++i) cellBase[t * 16 + i] = base + loc[i];
}

// scatter segment blk using LDS cursors; zero global atomics
__device__ __forceinline__ void scatter_role(int blk, int t,
    const float* __restrict__ coords, const u32* __restrict__ T,
    const u32* __restrict__ cellBase, vf4* __restrict__ rc2, u32* cur)
{
#pragma unroll
    for (int i = 0; i < NCELL / 256; ++i) {
        int cell = t + 256 * i;
        cur[cell] = cellBase[cell] + T[(u32)cell * NB + blk];
    }
    __syncthreads();
    int lim = (blk + 1) * SEG;
#pragma unroll 1
    for (int it = 0; it < (SEG + 255) / 256; ++it) {
        int idx = blk * SEG + it * 256 + t;
        if (idx < lim) {
            float x = ntl(&coords[3 * idx + 0]);
            float y = ntl(&coords[3 * idx + 1]);
            float z = ntl(&coords[3 * idx + 2]);
            u32 pos = atomicAdd(&cur[cellOf(x, y, z)], 1u);   // LDS atomic
            vf4 v; v.x = x; v.y = y; v.z = z; v.w = __uint_as_float((u32)idx);
            __builtin_nontemporal_store(v, rc2 + pos);
        }
    }
}

// ================= cooperative all-in-one prep kernel ========================
// 4 phases, 3 grid syncs; transpose tiles fill every non-binning block.
__global__ void __launch_bounds__(256, 4) prep_all(
    const float* __restrict__ coords,
    const float* __restrict__ p0, const float* __restrict__ p1,
    const float* __restrict__ p2,
    const float* __restrict__ lz, const float* __restrict__ ly,
    const float* __restrict__ lx,
    char* __restrict__ ws, u32* __restrict__ T,
    u32* __restrict__ cellTot, u32* __restrict__ cellBase,
    vf4* __restrict__ rc2)
{
    __shared__ u32 smem[NCELL + 8];
    cg::grid_group grid = cg::this_grid();
    int bid = blockIdx.x, t = threadIdx.x;

    // P1: count (blocks 0..63) || tp tiles [0, 2048)
    if (bid < NB) count_role(bid, t, coords, T, smem);
    else          tp_range(0, 2048, bid - NB, NBLK - NB, t, p0, p1, p2, ws, smem);
    grid.sync();

    // P2: within-cell prefix (blocks 0..15) || tp tiles [2048, 4096)
    if (bid < 16) prefix_role(bid, t, T, cellTot);
    else          tp_range(2048, 4096, bid - 16, NBLK - 16, t, p0, p1, p2, ws, smem);
    grid.sync();

    // P3: global base scan (block 0) || tp tiles [4096, 5120)
    if (bid == 0) base_role(t, cellTot, cellBase, smem);
    else          tp_range(4096, 5120, bid - 1, NBLK - 1, t, p0, p1, p2, ws, smem);
    grid.sync();

    // P4: scatter (0..63) || lines (64..69) || tp tiles [5120, 6144)
    if (bid < NB)          scatter_role(bid, t, coords, T, cellBase, rc2, smem);
    else if (bid < NB + 6) lines_role(bid - NB, t, lz, ly, lx, ws);
    else                   tp_range(5120, NTILE, bid - NB - 6, NBLK - NB - 6, t,
                                    p0, p1, p2, ws, smem);
}

// ================= serial fallbacks (same roles) =============================
__global__ __launch_bounds__(256) void ser_tp(
    const float* __restrict__ p0, const float* __restrict__ p1,
    const float* __restrict__ p2, char* __restrict__ ws)
{
    __shared__ u32 smem[NCELL + 8];
    tp_role(blockIdx.x, threadIdx.x, p0, p1, p2, ws, smem);
}
__global__ __launch_bounds__(256) void ser_lines(
    const float* __restrict__ lz, const float* __restrict__ ly,
    const float* __restrict__ lx, char* __restrict__ ws)
{
    lines_role(blockIdx.x, threadIdx.x, lz, ly, lx, ws);
}
__global__ __launch_bounds__(256) void ser_count(
    const float* __restrict__ coords, u32* __restrict__ T)
{
    __shared__ u32 smem[NCELL + 8];
    count_role(blockIdx.x, threadIdx.x, coords, T, smem);
}
__global__ __launch_bounds__(256) void ser_prefix(
    u32* __restrict__ T, u32* __restrict__ cellTot)
{
    prefix_role(blockIdx.x, threadIdx.x, T, cellTot);
}
__global__ __launch_bounds__(256) void ser_base(
    const u32* __restrict__ cellTot, u32* __restrict__ cellBase)
{
    __shared__ u32 smem[NCELL + 8];
    base_role(threadIdx.x, cellTot, cellBase, smem);
}
__global__ __launch_bounds__(256) void ser_scatter(
    const float* __restrict__ coords, const u32* __restrict__ T,
    const u32* __restrict__ cellBase, vf4* __restrict__ rc2)
{
    __shared__ u32 smem[NCELL + 8];
    scatter_role(blockIdx.x, threadIdx.x, coords, T, cellBase, rc2, smem);
}

// ---------- unsorted-path transposes (small-ws fallback) --------------------
template <int TEXB>
__global__ __launch_bounds__(256) void transpose_planes(
    const float* __restrict__ p0, const float* __restrict__ p1,
    const float* __restrict__ p2, char* __restrict__ ws)
{
    __shared__ u32 lds[TT * TS + 8];
    int t = threadIdx.x;
    int base = blockIdx.x * TT;
    int plane = blockIdx.y;
    const float* src = (plane == 0) ? p0 : ((plane == 1) ? p1 : p2);
    int xi = t & 31, dg = t >> 5;
#pragma unroll
    for (int j = 0; j < 3; ++j) {
        int d = dg + 8 * j;
        vf4 a = ntl4(src + (size_t)(2 * d) * TEXELS + base + 4 * xi);
        vf4 b = ntl4(src + (size_t)(2 * d + 1) * TEXELS + base + 4 * xi);
        lds[(4 * xi + 0) * TS + d] = pkbf(a.x, b.x);
        lds[(4 * xi + 1) * TS + d] = pkbf(a.y, b.y);
        lds[(4 * xi + 2) * TS + d] = pkbf(a.z, b.z);
        lds[(4 * xi + 3) * TS + d] = pkbf(a.w, b.w);
    }
    __syncthreads();
    char* outp = ws + (size_t)plane * TEXELS * TEXB + (size_t)base * TEXB;
    constexpr int NS = TT * TEXB / (16 * 256);
#pragma unroll
    for (int s = 0; s < NS; ++s) {
        u32 o = (u32)(s * 256 + t) * 16u;
        u32 texel, rem;
        if (TEXB == 128) { texel = o >> 7; rem = o & 127u; }
        else { texel = ((o >> 5) * 43691u) >> 17; rem = o - texel * 96u; }
        u32 dw = texel * TS + (rem >> 2);
        uint4 q = make_uint4(lds[dw], lds[dw + 1], lds[dw + 2], lds[dw + 3]);
        *(uint4*)(outp + o) = q;
    }
}

template <int TEXB>
__global__ __launch_bounds__(256) void transpose_lines_t(
    const float* __restrict__ lz, const float* __restrict__ ly,
    const float* __restrict__ lx, char* __restrict__ ws)
{
    int id = blockIdx.x * 256 + threadIdx.x;
    int line = id >> 9;
    int pos = id & (RES - 1);
    const float* src = (line == 0) ? lz : ((line == 1) ? ly : lx);
    char* dst = ws + (size_t)3 * TEXELS * TEXB + (size_t)line * RES * TEXB
                   + (size_t)pos * TEXB;
#pragma unroll
    for (int k = 0; k < 6; ++k) {
        uint4 q;
        q.x = pkbf(ntl(&src[(8 * k + 0) * RES + pos]), ntl(&src[(8 * k + 1) * RES + pos]));
        q.y = pkbf(ntl(&src[(8 * k + 2) * RES + pos]), ntl(&src[(8 * k + 3) * RES + pos]));
        q.z = pkbf(ntl(&src[(8 * k + 4) * RES + pos]), ntl(&src[(8 * k + 5) * RES + pos]));
        q.w = pkbf(ntl(&src[(8 * k + 6) * RES + pos]), ntl(&src[(8 * k + 7) * RES + pos]));
        *(uint4*)(dst + 16 * k) = q;
    }
}

// ---------- Pass 2: gather + interpolate (8 lanes/pt) + LDS + project -------
__device__ __forceinline__ void prep1(float g, int& i0, int& i1, float& w) {
    float p = fminf(fmaxf((g + 1.f) * 0.5f * 511.f, 0.f), 511.f);
    float fp = floorf(p);
    i0 = (int)fp;
    i1 = min(i0 + 1, RES - 1);
    w = p - fp;
}

// SORTED: cin = rc2 (vf4: x,y,z,bits(orig)); else cin = raw coords (float*3).
template <int TEXB, bool SORTED>
__global__ __launch_bounds__(512, 4) void geo_main(
    const void* __restrict__ cin, const char* __restrict__ ws,
    const float* __restrict__ W, const float* __restrict__ Bb,
    float* __restrict__ out)
{
    __shared__ float vm_lds[PPB * VMS];
    __shared__ u32 opt_lds[PPB];

    int tid = threadIdx.x;
    int ptL = tid >> 3;
    int c = tid & 7;

    int bid = blockIdx.x;
    if (SORTED) {
        int nwg = gridDim.x;                        // 15625
        int q = nwg >> 3, r = nwg & 7;
        int xcd = bid & 7, slot = bid >> 3;
        bid = (xcd < r ? xcd * (q + 1) : r * (q + 1) + (xcd - r) * q) + slot;
    }
    int pt = bid * PPB + ptL;

    float gx, gy, gz;
    if (SORTED) {
        vf4 cc = __builtin_nontemporal_load((const vf4*)cin + pt);
        gx = cc.x * 2.f - 1.f;
        gy = cc.y * 2.f - 1.f;
        gz = cc.z * 2.f - 1.f;
        if (c == 0) opt_lds[ptL] = __float_as_uint(cc.w);
    } else {
        const float* coords = (const float*)cin;
        gx = ntl(&coords[3 * pt + 0]) * 2.f - 1.f;
        gy = ntl(&coords[3 * pt + 1]) * 2.f - 1.f;
        gz = ntl(&coords[3 * pt + 2]) * 2.f - 1.f;
        if (c == 0) opt_lds[ptL] = (u32)pt;
    }

    int x0, x1, y0, y1, z0, z1;
    float wx, wy, wz;
    prep1(gx, x0, x1, wx);
    prep1(gy, y0, y1, wy);
    prep1(gz, z0, z1, wz);

    const size_t PW = (size_t)TEXELS * TEXB;
    const size_t LW = (size_t)RES * TEXB;
    const char* pxy = ws;
    const char* pxz = ws + PW;
    const char* pyz = ws + 2 * PW;
    const char* lzb = ws + 3 * PW;
    const char* lyb = lzb + LW;
    const char* lxb = lyb + LW;

    u32 co = 12u * (u32)c;

    u32 q[12][3], le[3][3], lf[3][3];
    {
        u32 offs[12];
        offs[0] = (u32)(y0 * RES + x0) * TEXB + co;
        offs[1] = (u32)(y0 * RES + x1) * TEXB + co;
        offs[2] = (u32)(y1 * RES + x0) * TEXB + co;
        offs[3] = (u32)(y1 * RES + x1) * TEXB + co;
        offs[4] = (u32)(z0 * RES + x0) * TEXB + co;
        offs[5] = (u32)(z0 * RES + x1) * TEXB + co;
        offs[6] = (u32)(z1 * RES + x0) * TEXB + co;
        offs[7] = (u32)(z1 * RES + x1) * TEXB + co;
        offs[8]  = (u32)(z0 * RES + y0) * TEXB + co;
        offs[9]  = (u32)(z0 * RES + y1) * TEXB + co;
        offs[10] = (u32)(z1 * RES + y0) * TEXB + co;
        offs[11] = (u32)(z1 * RES + y1) * TEXB + co;
        const char* bases[3] = { pxy, pxz, pyz };
#pragma unroll
        for (int p = 0; p < 3; ++p) {
#pragma unroll
            for (int k = 0; k < 4; ++k) {
                const u32* s = (const u32*)(bases[p] + offs[4 * p + k]);
                q[4 * p + k][0] = s[0];
                q[4 * p + k][1] = s[1];
                q[4 * p + k][2] = s[2];
            }
        }
        const char* lb[3] = { lzb, lyb, lxb };
        u32 l0[3] = { (u32)z0 * TEXB + co, (u32)y0 * TEXB + co, (u32)x0 * TEXB + co };
        u32 l1[3] = { (u32)z1 * TEXB + co, (u32)y1 * TEXB + co, (u32)x1 * TEXB + co };
#pragma unroll
        for (int p = 0; p < 3; ++p) {
            const u32* s0 = (const u32*)(lb[p] + l0[p]);
            const u32* s1 = (const u32*)(lb[p] + l1[p]);
            le[p][0] = s0[0]; le[p][1] = s0[1]; le[p][2] = s0[2];
            lf[p][0] = s1[0]; lf[p][1] = s1[1]; lf[p][2] = s1[2];
        }
    }

    float pw[3][4];
    pw[0][0] = (1.f - wy) * (1.f - wx); pw[0][1] = (1.f - wy) * wx;
    pw[0][2] = wy * (1.f - wx);         pw[0][3] = wy * wx;
    pw[1][0] = (1.f - wz) * (1.f - wx); pw[1][1] = (1.f - wz) * wx;
    pw[1][2] = wz * (1.f - wx);         pw[1][3] = wz * wx;
    pw[2][0] = (1.f - wz) * (1.f - wy); pw[2][1] = (1.f - wz) * wy;
    pw[2][2] = wz * (1.f - wy);         pw[2][3] = wz * wy;
    float lw[3] = { wz, wy, wx };

    float vm[6] = { 0.f, 0.f, 0.f, 0.f, 0.f, 0.f };
#pragma unroll
    for (int p = 0; p < 3; ++p) {
        float s0 = pw[p][0], s1 = pw[p][1], s2 = pw[p][2], s3 = pw[p][3];
        float il = 1.f - lw[p], wl = lw[p];
#pragma unroll
        for (int d = 0; d < 3; ++d) {
            u32 a = q[4 * p + 0][d], b = q[4 * p + 1][d];
            u32 cc = q[4 * p + 2][d], dd = q[4 * p + 3][d];
            float slo = s0 * lobf(a) + s1 * lobf(b) + s2 * lobf(cc) + s3 * lobf(dd);
            float shi = s0 * hibf(a) + s1 * hibf(b) + s2 * hibf(cc) + s3 * hibf(dd);
            float llo = il * lobf(le[p][d]) + wl * lobf(lf[p][d]);
            float lhi = il * hibf(le[p][d]) + wl * hibf(lf[p][d]);
            vm[2 * d + 0] = fmaf(slo, llo, vm[2 * d + 0]);
            vm[2 * d + 1] = fmaf(shi, lhi, vm[2 * d + 1]);
        }
    }

    float* vr = vm_lds + ptL * VMS + 6 * c;
    *(float2*)(vr + 0) = make_float2(vm[0], vm[1]);
    *(float2*)(vr + 2) = make_float2(vm[2], vm[3]);
    *(float2*)(vr + 4) = make_float2(vm[4], vm[5]);

    __syncthreads();

    int wav = __builtin_amdgcn_readfirstlane(tid >> 6);
    int lane = tid & 63;
    int ob = wav * 4;

    const float* vmrow = vm_lds + lane * VMS;
    float4 bb = *(const float4*)(Bb + ob);
    float a0 = bb.x, a1 = bb.y, a2 = bb.z, a3 = bb.w;
#pragma unroll 4
    for (int k = 0; k < 12; ++k) {
        float4 v = *(const float4*)(vmrow + 4 * k);
        float4 w0 = *(const float4*)(W + (ob + 0) * RANK + 4 * k);
        float4 w1 = *(const float4*)(W + (ob + 1) * RANK + 4 * k);
        float4 w2 = *(const float4*)(W + (ob + 2) * RANK + 4 * k);
        float4 w3 = *(const float4*)(W + (ob + 3) * RANK + 4 * k);
        a0 = fmaf(v.x, w0.x, a0); a0 = fmaf(v.y, w0.y, a0);
        a0 = fmaf(v.z, w0.z, a0); a0 = fmaf(v.w, w0.w, a0);
        a1 = fmaf(v.x, w1.x, a1); a1 = fmaf(v.y, w1.y, a1);
        a1 = fmaf(v.z, w1.z, a1); a1 = fmaf(v.w, w1.w, a1);
        a2 = fmaf(v.x, w2.x, a2); a2 = fmaf(v.y, w2.y, a2);
        a2 = fmaf(v.z, w2.z, a2); a2 = fmaf(v.w, w2.w, a2);
        a3 = fmaf(v.x, w3.x, a3); a3 = fmaf(v.y, w3.y, a3);
        a3 = fmaf(v.z, w3.z, a3); a3 = fmaf(v.w, w3.w, a3);
    }

    __syncthreads();
    {
        vf4 r; r.x = a0; r.y = a1; r.z = a2; r.w = a3;
        *(vf4*)(vm_lds + lane * OSTR + ob) = r;
    }
    __syncthreads();
    {
        int p8 = lane >> 3;
        int c2 = lane & 7;
        int gp = wav * 8 + p8;
        vf4 v = *(const vf4*)(vm_lds + gp * OSTR + 4 * c2);
        size_t orow = (size_t)opt_lds[gp];
        __builtin_nontemporal_store(v, (vf4*)(out + orow * ODIM + 4 * c2));
    }
}

// ---------- Launch ----------------------------------------------------------
template <int TEXB>
static void launch_unsorted(const float* coords, const float* pxy, const float* pxz,
                            const float* pyz, const float* lz, const float* ly,
                            const float* lx, const float* W, const float* Bb,
                            float* out, char* ws, hipStream_t stream) {
    dim3 gt(TEXELS / TT, 3);
    transpose_planes<TEXB><<<gt, 256, 0, stream>>>(pxy, pxz, pyz, ws);
    transpose_lines_t<TEXB><<<6, 256, 0, stream>>>(lz, ly, lx, ws);
    geo_main<TEXB, false><<<NPTS / PPB, 512, 0, stream>>>(coords, ws, W, Bb, out);
}

extern "C" void kernel_launch(void* const* d_in, const int* in_sizes, int n_in,
                              void* d_out, int out_size, void* d_ws, size_t ws_size,
                              hipStream_t stream) {
    const float* coords = (const float*)d_in[0];
    const float* pxy = (const float*)d_in[1];
    const float* pxz = (const float*)d_in[2];
    const float* pyz = (const float*)d_in[3];
    const float* lz = (const float*)d_in[4];
    const float* ly = (const float*)d_in[5];
    const float* lx = (const float*)d_in[6];
    const float* W = (const float*)d_in[7];
    const float* Bb = (const float*)d_in[8];
    float* out = (float*)d_out;
    char* ws = (char*)d_ws;

    // sorted path layout (TEXB=96)
    size_t pool96 = (size_t)3 * TEXELS * 96 + (size_t)3 * RES * 96;   // 75,644,928
    size_t o_T = (pool96 + 255) & ~(size_t)255;
    size_t o_ct = o_T + (size_t)NCELL * NB * 4;     // T: 1 MB
    size_t o_cb = o_ct + (size_t)NCELL * 4;         // cellTot: 16 KB
    size_t o_rc2 = o_cb + (size_t)NCELL * 4;        // cellBase: 16 KB
    size_t need_sorted = o_rc2 + (size_t)NPTS * 16; // ~92.7 MB
    size_t need128 = (size_t)3 * TEXELS * 128 + (size_t)3 * RES * 128;

    if (ws_size >= need_sorted) {
        u32* T = (u32*)(ws + o_T);
        u32* cellTot = (u32*)(ws + o_ct);
        u32* cellBase = (u32*)(ws + o_cb);
        vf4* rc2 = (vf4*)(ws + o_rc2);

        void* args[] = { (void*)&coords, (void*)&pxy, (void*)&pxz, (void*)&pyz,
                         (void*)&lz, (void*)&ly, (void*)&lx,
                         (void*)&ws, (void*)&T, (void*)&cellTot,
                         (void*)&cellBase, (void*)&rc2 };
        hipError_t err = hipLaunchCooperativeKernel(
            (const void*)prep_all, dim3(NBLK), dim3(256), args, 0, stream);
        if (err != hipSuccess) {
            // serial fallback: same roles, 6 dispatches
            ser_tp<<<NTILE, 256, 0, stream>>>(pxy, pxz, pyz, ws);
            ser_lines<<<6, 256, 0, stream>>>(lz, ly, lx, ws);
            ser_count<<<NB, 256, 0, stream>>>(coords, T);
            ser_prefix<<<16, 256, 0, stream>>>(T, cellTot);
            ser_base<<<1, 256, 0, stream>>>(cellTot, cellBase);
            ser_scatter<<<NB, 256, 0, stream>>>(coords, T, cellBase, rc2);
        }
        geo_main<96, true><<<NPTS / PPB, 512, 0, stream>>>(rc2, ws, W, Bb, out);
    } else if (ws_size >= need128) {
        launch_unsorted<128>(coords, pxy, pxz, pyz, lz, ly, lx, W, Bb, out, ws, stream);
    } else {
        launch_unsorted<96>(coords, pxy, pxz, pyz, lz, ly, lx, W, Bb, out, ws, stream);
    }
}

// Round 6
// 474.824 us; speedup vs baseline: 1.7644x; 1.7644x over previous
//
#include <hip/hip_runtime.h>
#include <stdint.h>

#define RES      512
#define TEXELS   (RES * RES)          // 262144
#define NPTS     1000000
#define RANK     48
#define ODIM     32
#define PPB      64                   // points per block (geo_main)
#define VMS      52                   // vm LDS row stride (floats), pad 48->52
#define OSTR     33                   // out-staging LDS row stride
#define CELLS    32768                // 32x32x32 Morton cells (R3's best geo order)
#define LINB     6                    // line-transpose blocks in K1
#define CNTB     256                  // count blocks in K1 (grid-stride)
#define TPB      1536                 // streaming-transpose blocks in K1 (2 iters exact)
#define SCTB     1024                 // scatter blocks

typedef unsigned int u32;
typedef float vf4 __attribute__((ext_vector_type(4)));

__device__ __forceinline__ float lobf(u32 u) { return __uint_as_float(u << 16); }
__device__ __forceinline__ float hibf(u32 u) { return __uint_as_float(u & 0xffff0000u); }

__device__ __forceinline__ float ntl(const float* p) {
    return __builtin_nontemporal_load(p);
}

// RNE pack two fp32 -> bf16x2 (a low, b high)
__device__ __forceinline__ u32 pkbf(float a, float b) {
    u32 x = __float_as_uint(a), y = __float_as_uint(b);
    u32 xr = (x + 0x7fffu + ((x >> 16) & 1u)) >> 16;
    u32 yr = (y + 0x7fffu + ((y >> 16) & 1u)) & 0xffff0000u;
    return xr | yr;
}

// ---------- Morton cell id, 32^3 (identical in count & scatter) -------------
__device__ __forceinline__ u32 sprd5(u32 a) {
    a &= 31u;
    a = (a | (a << 8)) & 0x100Fu;
    a = (a | (a << 4)) & 0x10C3u;
    a = (a | (a << 2)) & 0x1249u;
    return a;
}
__device__ __forceinline__ u32 cellOf(float x, float y, float z) {
    u32 cx = (u32)fminf(fmaxf(x * 32.f, 0.f), 31.f);
    u32 cy = (u32)fminf(fmaxf(y * 32.f, 0.f), 31.f);
    u32 cz = (u32)fminf(fmaxf(z * 32.f, 0.f), 31.f);
    return sprd5(cx) | (sprd5(cy) << 1) | (sprd5(cz) << 2);   // < 32768
}

// ---------- streaming transpose: one texel, no LDS, no barriers -------------
// Reads 48 channels (each wave-coalesced 256B stream), packs 24 bf16x2 dwords
// in registers (24 loads in flight per half-batch), writes 96B contiguous.
__device__ __forceinline__ void tp_one(int g,
    const float* __restrict__ p0, const float* __restrict__ p1,
    const float* __restrict__ p2, char* __restrict__ ws)
{
    int plane = g >> 18;                            // g in [0, 3*TEXELS)
    int texel = g & (TEXELS - 1);
    const float* src = (plane == 0) ? p0 : ((plane == 1) ? p1 : p2);
    u32 c2[24];
#pragma unroll
    for (int h = 0; h < 2; ++h) {
        float fa[12], fb[12];
#pragma unroll
        for (int d = 0; d < 12; ++d) {              // 24 independent loads batch
            fa[d] = ntl(src + (size_t)(2 * (h * 12 + d) + 0) * TEXELS + texel);
            fb[d] = ntl(src + (size_t)(2 * (h * 12 + d) + 1) * TEXELS + texel);
        }
#pragma unroll
        for (int d = 0; d < 12; ++d) c2[h * 12 + d] = pkbf(fa[d], fb[d]);
    }
    char* dst = ws + (size_t)plane * TEXELS * 96 + (size_t)texel * 96;
#pragma unroll
    for (int s = 0; s < 6; ++s) {
        uint4 q = make_uint4(c2[4 * s + 0], c2[4 * s + 1],
                             c2[4 * s + 2], c2[4 * s + 3]);
        *(uint4*)(dst + 16 * s) = q;
    }
}

// ---------- line transpose role (6 blocks cover 3 lines x 512 pos) ----------
__device__ __forceinline__ void lines_role(int j, int t,
    const float* __restrict__ lz, const float* __restrict__ ly,
    const float* __restrict__ lx, char* __restrict__ ws)
{
    int id = j * 256 + t;
    int line = id >> 9;
    int pos = id & (RES - 1);
    const float* src = (line == 0) ? lz : ((line == 1) ? ly : lx);
    char* dst = ws + (size_t)3 * TEXELS * 96 + (size_t)line * RES * 96
                   + (size_t)pos * 96;
#pragma unroll
    for (int k = 0; k < 6; ++k) {
        uint4 q;
        q.x = pkbf(ntl(&src[(8 * k + 0) * RES + pos]), ntl(&src[(8 * k + 1) * RES + pos]));
        q.y = pkbf(ntl(&src[(8 * k + 2) * RES + pos]), ntl(&src[(8 * k + 3) * RES + pos]));
        q.z = pkbf(ntl(&src[(8 * k + 4) * RES + pos]), ntl(&src[(8 * k + 5) * RES + pos]));
        q.w = pkbf(ntl(&src[(8 * k + 6) * RES + pos]), ntl(&src[(8 * k + 7) * RES + pos]));
        *(uint4*)(dst + 16 * k) = q;
    }
}

// ---------- K1: lines || count || streaming-transpose (independent roles) ---
__global__ __launch_bounds__(256) void k1_prep(
    const float* __restrict__ coords, u32* __restrict__ counts,
    const float* __restrict__ p0, const float* __restrict__ p1,
    const float* __restrict__ p2,
    const float* __restrict__ lz, const float* __restrict__ ly,
    const float* __restrict__ lx, char* __restrict__ ws)
{
    int bx = blockIdx.x, t = threadIdx.x;
    if (bx < LINB) {
        lines_role(bx, t, lz, ly, lx, ws);
    } else if (bx < LINB + CNTB) {
        // histogram count, grid-stride, global atomics (32K cells, L2-resident)
        for (int idx = (bx - LINB) * 256 + t; idx < NPTS; idx += CNTB * 256) {
            float x = ntl(&coords[3 * idx + 0]);
            float y = ntl(&coords[3 * idx + 1]);
            float z = ntl(&coords[3 * idx + 2]);
            atomicAdd(&counts[cellOf(x, y, z)], 1u);
        }
    } else {
        int w = bx - LINB - CNTB;                   // 0..TPB-1
        for (int g = w * 256 + t; g < 3 * TEXELS; g += TPB * 256)
            tp_one(g, p0, p1, p2, ws);              // exactly 2 iterations
    }
}

// ---------- K2: exclusive prefix over CELLS (1 block x 1024 threads) --------
__global__ __launch_bounds__(1024) void k2_scan(
    const u32* __restrict__ counts, u32* __restrict__ cursors)
{
    __shared__ u32 wt[16];
    int t = threadIdx.x;
    u32 local[32];
    u32 s = 0;
#pragma unroll
    for (int i = 0; i < 32; ++i) {
        local[i] = s;                               // exclusive within thread
        s += counts[t * 32 + i];
    }
    u32 tot = s;
    int lane = t & 63, w = t >> 6;
    u32 incl = tot;
#pragma unroll
    for (int d = 1; d < 64; d <<= 1) {
        u32 v = __shfl_up(incl, d);
        if (lane >= d) incl += v;
    }
    if (lane == 63) wt[w] = incl;
    __syncthreads();
    if (t == 0) {
        u32 a = 0;
#pragma unroll
        for (int i = 0; i < 16; ++i) { u32 x = wt[i]; wt[i] = a; a += x; }
    }
    __syncthreads();
    u32 base = wt[w] + (incl - tot);
#pragma unroll
    for (int i = 0; i < 32; ++i)
        cursors[t * 32 + i] = base + local[i];
}

// ---------- K3: scatter into rc2 = (x,y,z,bits(origPt)) ---------------------
__global__ __launch_bounds__(256) void k3_scatter(
    const float* __restrict__ coords, u32* __restrict__ cursors,
    vf4* __restrict__ rc2)
{
    int t = threadIdx.x;
    for (int idx = blockIdx.x * 256 + t; idx < NPTS; idx += SCTB * 256) {
        float x = ntl(&coords[3 * idx + 0]);
        float y = ntl(&coords[3 * idx + 1]);
        float z = ntl(&coords[3 * idx + 2]);
        u32 pos = atomicAdd(&cursors[cellOf(x, y, z)], 1u);
        vf4 v; v.x = x; v.y = y; v.z = z; v.w = __uint_as_float((u32)idx);
        __builtin_nontemporal_store(v, rc2 + pos);
    }
}

// ---------- unsorted fallback transposes ------------------------------------
__global__ __launch_bounds__(256) void tp_stream_only(
    const float* __restrict__ p0, const float* __restrict__ p1,
    const float* __restrict__ p2, char* __restrict__ ws)
{
    int g = blockIdx.x * 256 + threadIdx.x;         // grid = 3*TEXELS/256
    tp_one(g, p0, p1, p2, ws);
}
__global__ __launch_bounds__(256) void lines_only(
    const float* __restrict__ lz, const float* __restrict__ ly,
    const float* __restrict__ lx, char* __restrict__ ws)
{
    lines_role(blockIdx.x, threadIdx.x, lz, ly, lx, ws);
}

// ---------- Pass 2: gather + interpolate (8 lanes/pt) + LDS + project -------
// Verbatim R3 structure (123 us, VGPR 36).
__device__ __forceinline__ void prep1(float g, int& i0, int& i1, float& w) {
    float p = fminf(fmaxf((g + 1.f) * 0.5f * 511.f, 0.f), 511.f);
    float fp = floorf(p);
    i0 = (int)fp;
    i1 = min(i0 + 1, RES - 1);
    w = p - fp;
}

// SORTED: cin = rc2 (vf4: x,y,z,bits(orig)); else cin = raw coords (float*3).
template <int TEXB, bool SORTED>
__global__ __launch_bounds__(512, 4) void geo_main(
    const void* __restrict__ cin, const char* __restrict__ ws,
    const float* __restrict__ W, const float* __restrict__ Bb,
    float* __restrict__ out)
{
    __shared__ float vm_lds[PPB * VMS];             // 13.3 KB (reused for staging)
    __shared__ u32 opt_lds[PPB];                    // orig point id per local point

    int tid = threadIdx.x;
    int ptL = tid >> 3;                             // 0..63
    int c = tid & 7;                                // chunk: ch 6c..6c+5

    int bid = blockIdx.x;
    if (SORTED) {
        // XCD-chunked bijective swizzle: consecutive Morton blocks share an XCD
        int nwg = gridDim.x;                        // 15625
        int q = nwg >> 3, r = nwg & 7;
        int xcd = bid & 7, slot = bid >> 3;
        bid = (xcd < r ? xcd * (q + 1) : r * (q + 1) + (xcd - r) * q) + slot;
    }
    int pt = bid * PPB + ptL;                       // NPTS = 15625*64 exactly

    float gx, gy, gz;
    if (SORTED) {
        vf4 cc = __builtin_nontemporal_load((const vf4*)cin + pt);
        gx = cc.x * 2.f - 1.f;
        gy = cc.y * 2.f - 1.f;
        gz = cc.z * 2.f - 1.f;
        if (c == 0) opt_lds[ptL] = __float_as_uint(cc.w);
    } else {
        const float* coords = (const float*)cin;
        gx = ntl(&coords[3 * pt + 0]) * 2.f - 1.f;
        gy = ntl(&coords[3 * pt + 1]) * 2.f - 1.f;
        gz = ntl(&coords[3 * pt + 2]) * 2.f - 1.f;
        if (c == 0) opt_lds[ptL] = (u32)pt;
    }

    int x0, x1, y0, y1, z0, z1;
    float wx, wy, wz;
    prep1(gx, x0, x1, wx);
    prep1(gy, y0, y1, wy);
    prep1(gz, z0, z1, wz);

    const size_t PW = (size_t)TEXELS * TEXB;
    const size_t LW = (size_t)RES * TEXB;
    const char* pxy = ws;
    const char* pxz = ws + PW;
    const char* pyz = ws + 2 * PW;
    const char* lzb = ws + 3 * PW;
    const char* lyb = lzb + LW;
    const char* lxb = lyb + LW;

    u32 co = 12u * (u32)c;                          // byte offset of chunk in texel

    u32 q[12][3], le[3][3], lf[3][3];
    {
        u32 offs[12];
        offs[0] = (u32)(y0 * RES + x0) * TEXB + co;
        offs[1] = (u32)(y0 * RES + x1) * TEXB + co;
        offs[2] = (u32)(y1 * RES + x0) * TEXB + co;
        offs[3] = (u32)(y1 * RES + x1) * TEXB + co;
        offs[4] = (u32)(z0 * RES + x0) * TEXB + co;
        offs[5] = (u32)(z0 * RES + x1) * TEXB + co;
        offs[6] = (u32)(z1 * RES + x0) * TEXB + co;
        offs[7] = (u32)(z1 * RES + x1) * TEXB + co;
        offs[8]  = (u32)(z0 * RES + y0) * TEXB + co;
        offs[9]  = (u32)(z0 * RES + y1) * TEXB + co;
        offs[10] = (u32)(z1 * RES + y0) * TEXB + co;
        offs[11] = (u32)(z1 * RES + y1) * TEXB + co;
        const char* bases[3] = { pxy, pxz, pyz };
#pragma unroll
        for (int p = 0; p < 3; ++p) {
#pragma unroll
            for (int k = 0; k < 4; ++k) {
                const u32* s = (const u32*)(bases[p] + offs[4 * p + k]);
                q[4 * p + k][0] = s[0];
                q[4 * p + k][1] = s[1];
                q[4 * p + k][2] = s[2];
            }
        }
        const char* lb[3] = { lzb, lyb, lxb };
        u32 l0[3] = { (u32)z0 * TEXB + co, (u32)y0 * TEXB + co, (u32)x0 * TEXB + co };
        u32 l1[3] = { (u32)z1 * TEXB + co, (u32)y1 * TEXB + co, (u32)x1 * TEXB + co };
#pragma unroll
        for (int p = 0; p < 3; ++p) {
            const u32* s0 = (const u32*)(lb[p] + l0[p]);
            const u32* s1 = (const u32*)(lb[p] + l1[p]);
            le[p][0] = s0[0]; le[p][1] = s0[1]; le[p][2] = s0[2];
            lf[p][0] = s1[0]; lf[p][1] = s1[1]; lf[p][2] = s1[2];
        }
    }

    float pw[3][4];
    pw[0][0] = (1.f - wy) * (1.f - wx); pw[0][1] = (1.f - wy) * wx;
    pw[0][2] = wy * (1.f - wx);         pw[0][3] = wy * wx;
    pw[1][0] = (1.f - wz) * (1.f - wx); pw[1][1] = (1.f - wz) * wx;
    pw[1][2] = wz * (1.f - wx);         pw[1][3] = wz * wx;
    pw[2][0] = (1.f - wz) * (1.f - wy); pw[2][1] = (1.f - wz) * wy;
    pw[2][2] = wz * (1.f - wy);         pw[2][3] = wz * wy;
    float lw[3] = { wz, wy, wx };

    float vm[6] = { 0.f, 0.f, 0.f, 0.f, 0.f, 0.f };
#pragma unroll
    for (int p = 0; p < 3; ++p) {
        float s0 = pw[p][0], s1 = pw[p][1], s2 = pw[p][2], s3 = pw[p][3];
        float il = 1.f - lw[p], wl = lw[p];
#pragma unroll
        for (int d = 0; d < 3; ++d) {               // dword d -> ch 2d, 2d+1
            u32 a = q[4 * p + 0][d], b = q[4 * p + 1][d];
            u32 cc = q[4 * p + 2][d], dd = q[4 * p + 3][d];
            float slo = s0 * lobf(a) + s1 * lobf(b) + s2 * lobf(cc) + s3 * lobf(dd);
            float shi = s0 * hibf(a) + s1 * hibf(b) + s2 * hibf(cc) + s3 * hibf(dd);
            float llo = il * lobf(le[p][d]) + wl * lobf(lf[p][d]);
            float lhi = il * hibf(le[p][d]) + wl * hibf(lf[p][d]);
            vm[2 * d + 0] = fmaf(slo, llo, vm[2 * d + 0]);
            vm[2 * d + 1] = fmaf(shi, lhi, vm[2 * d + 1]);
        }
    }

    float* vr = vm_lds + ptL * VMS + 6 * c;
    *(float2*)(vr + 0) = make_float2(vm[0], vm[1]);
    *(float2*)(vr + 2) = make_float2(vm[2], vm[3]);
    *(float2*)(vr + 4) = make_float2(vm[4], vm[5]);

    __syncthreads();

    int wav = __builtin_amdgcn_readfirstlane(tid >> 6);   // 0..7, wave-uniform
    int lane = tid & 63;                                  // local point
    int ob = wav * 4;

    const float* vmrow = vm_lds + lane * VMS;
    float4 bb = *(const float4*)(Bb + ob);                // uniform -> s_load
    float a0 = bb.x, a1 = bb.y, a2 = bb.z, a3 = bb.w;
#pragma unroll 4
    for (int k = 0; k < 12; ++k) {
        float4 v = *(const float4*)(vmrow + 4 * k);       // ds_read_b128
        float4 w0 = *(const float4*)(W + (ob + 0) * RANK + 4 * k);  // s_loads
        float4 w1 = *(const float4*)(W + (ob + 1) * RANK + 4 * k);
        float4 w2 = *(const float4*)(W + (ob + 2) * RANK + 4 * k);
        float4 w3 = *(const float4*)(W + (ob + 3) * RANK + 4 * k);
        a0 = fmaf(v.x, w0.x, a0); a0 = fmaf(v.y, w0.y, a0);
        a0 = fmaf(v.z, w0.z, a0); a0 = fmaf(v.w, w0.w, a0);
        a1 = fmaf(v.x, w1.x, a1); a1 = fmaf(v.y, w1.y, a1);
        a1 = fmaf(v.z, w1.z, a1); a1 = fmaf(v.w, w1.w, a1);
        a2 = fmaf(v.x, w2.x, a2); a2 = fmaf(v.y, w2.y, a2);
        a2 = fmaf(v.z, w2.z, a2); a2 = fmaf(v.w, w2.w, a2);
        a3 = fmaf(v.x, w3.x, a3); a3 = fmaf(v.y, w3.y, a3);
        a3 = fmaf(v.z, w3.z, a3); a3 = fmaf(v.w, w3.w, a3);
    }

    // ---- output staging: full 128B rows per wave; rows scattered by orig id
    __syncthreads();
    {
        vf4 r; r.x = a0; r.y = a1; r.z = a2; r.w = a3;
        *(vf4*)(vm_lds + lane * OSTR + ob) = r;
    }
    __syncthreads();
    {
        int p8 = lane >> 3;
        int c2 = lane & 7;
        int gp = wav * 8 + p8;
        vf4 v = *(const vf4*)(vm_lds + gp * OSTR + 4 * c2);
        size_t orow = (size_t)opt_lds[gp];
        __builtin_nontemporal_store(v, (vf4*)(out + orow * ODIM + 4 * c2));
    }
}

// ---------- Launch ----------------------------------------------------------
extern "C" void kernel_launch(void* const* d_in, const int* in_sizes, int n_in,
                              void* d_out, int out_size, void* d_ws, size_t ws_size,
                              hipStream_t stream) {
    const float* coords = (const float*)d_in[0];
    const float* pxy = (const float*)d_in[1];
    const float* pxz = (const float*)d_in[2];
    const float* pyz = (const float*)d_in[3];
    const float* lz = (const float*)d_in[4];
    const float* ly = (const float*)d_in[5];
    const float* lx = (const float*)d_in[6];
    const float* W = (const float*)d_in[7];
    const float* Bb = (const float*)d_in[8];
    float* out = (float*)d_out;
    char* ws = (char*)d_ws;

    size_t pool96 = (size_t)3 * TEXELS * 96 + (size_t)3 * RES * 96;   // 75,644,928
    size_t o_counts = (pool96 + 255) & ~(size_t)255;
    size_t o_cursors = o_counts + (size_t)CELLS * 4;                  // +128 KB
    size_t o_rc2 = o_cursors + (size_t)CELLS * 4;                     // +128 KB
    size_t need_sorted = o_rc2 + (size_t)NPTS * 16;                   // ~92.2 MB

    if (ws_size >= need_sorted) {
        u32* counts = (u32*)(ws + o_counts);
        u32* cursors = (u32*)(ws + o_cursors);
        vf4* rc2 = (vf4*)(ws + o_rc2);

        hipMemsetAsync(counts, 0, (size_t)CELLS * 4, stream);
        k1_prep<<<LINB + CNTB + TPB, 256, 0, stream>>>(coords, counts,
                                                       pxy, pxz, pyz,
                                                       lz, ly, lx, ws);
        k2_scan<<<1, 1024, 0, stream>>>(counts, cursors);
        k3_scatter<<<SCTB, 256, 0, stream>>>(coords, cursors, rc2);
        geo_main<96, true><<<NPTS / PPB, 512, 0, stream>>>(rc2, ws, W, Bb, out);
    } else {
        // unsorted fallback (small workspace): streaming tp + lines + geo
        tp_stream_only<<<3 * TEXELS / 256, 256, 0, stream>>>(pxy, pxz, pyz, ws);
        lines_only<<<6, 256, 0, stream>>>(lz, ly, lx, ws);
        geo_main<96, false><<<NPTS / PPB, 512, 0, stream>>>(coords, ws, W, Bb, out);
    }
}

// Round 7
// 466.241 us; speedup vs baseline: 1.7969x; 1.0184x over previous
//
#include <hip/hip_runtime.h>
#include <stdint.h>

#define RES      512
#define TEXELS   (RES * RES)          // 262144
#define NPTS     1000000
#define RANK     48
#define ODIM     32
#define PPB      64                   // points per block (geo_main)
#define VMS      52                   // vm LDS row stride (floats), pad 48->52
#define OSTR     33                   // out-staging LDS row stride
#define NCELL    4096                 // 16x16x16 Morton cells (LDS-histogram-able)
#define NSEG     256                  // binning segments (1 block/CU)
#define SEGSZ    3907                 // ceil(NPTS/NSEG); 256*3907 = 1,000,192
#define LINB     6                    // line-transpose blocks in K1
#define TPB4     768                  // tp blocks in K1: 3*TEXELS/4/256

typedef unsigned int u32;
typedef float vf4 __attribute__((ext_vector_type(4)));

__device__ __forceinline__ float lobf(u32 u) { return __uint_as_float(u << 16); }
__device__ __forceinline__ float hibf(u32 u) { return __uint_as_float(u & 0xffff0000u); }

__device__ __forceinline__ float ntl(const float* p) {
    return __builtin_nontemporal_load(p);
}
__device__ __forceinline__ vf4 ntl4(const float* p) {
    return __builtin_nontemporal_load((const vf4*)p);
}

// RNE pack two fp32 -> bf16x2 (a low, b high)
__device__ __forceinline__ u32 pkbf(float a, float b) {
    u32 x = __float_as_uint(a), y = __float_as_uint(b);
    u32 xr = (x + 0x7fffu + ((x >> 16) & 1u)) >> 16;
    u32 yr = (y + 0x7fffu + ((y >> 16) & 1u)) & 0xffff0000u;
    return xr | yr;
}

// ---------- Morton cell id, 16^3 (identical in count & scatter) -------------
__device__ __forceinline__ u32 sprd4(u32 a) {
    a &= 15u;
    a = (a | (a << 4)) & 0x0C3u;
    a = (a | (a << 2)) & 0x249u;
    return a;
}
__device__ __forceinline__ u32 cellOf(float x, float y, float z) {
    u32 cx = (u32)fminf(fmaxf(x * 16.f, 0.f), 15.f);
    u32 cy = (u32)fminf(fmaxf(y * 16.f, 0.f), 15.f);
    u32 cz = (u32)fminf(fmaxf(z * 16.f, 0.f), 15.f);
    return sprd4(cx) | (sprd4(cy) << 1) | (sprd4(cz) << 2);   // < 4096
}

// ---------- streaming transpose, 4 texels/thread, float4 loads --------------
// 16B/lane loads (1KB/wave-inst); per 16B chunk s (channels 8s..8s+7): 8 loads,
// 16 pkbf, 4 uint4 stores. No LDS, no barriers; stores merge in L2 (pool stays
// cache-warm for geo).
__device__ __forceinline__ void tp_one4(int g4,
    const float* __restrict__ p0, const float* __restrict__ p1,
    const float* __restrict__ p2, char* __restrict__ ws)
{
    int plane = g4 >> 16;                           // g4 in [0, 3*TEXELS/4)
    int t4 = g4 & (TEXELS / 4 - 1);                 // 65536 per plane
    const float* src = (plane == 0) ? p0 : ((plane == 1) ? p1 : p2);
    int tex0 = t4 * 4;
    char* dst = ws + (size_t)plane * TEXELS * 96 + (size_t)tex0 * 96;
#pragma unroll
    for (int s = 0; s < 6; ++s) {                   // 16B chunk of each texel
        vf4 fa[4], fb[4];
#pragma unroll
        for (int d = 0; d < 4; ++d) {               // dword 4s+d -> ch 2dd,2dd+1
            int dd = 4 * s + d;
            fa[d] = ntl4(src + (size_t)(2 * dd + 0) * TEXELS + tex0);
            fb[d] = ntl4(src + (size_t)(2 * dd + 1) * TEXELS + tex0);
        }
#pragma unroll
        for (int k = 0; k < 4; ++k) {               // texel tex0+k
            uint4 q = make_uint4(pkbf(fa[0][k], fb[0][k]),
                                 pkbf(fa[1][k], fb[1][k]),
                                 pkbf(fa[2][k], fb[2][k]),
                                 pkbf(fa[3][k], fb[3][k]));
            *(uint4*)(dst + (size_t)k * 96 + 16 * s) = q;
        }
    }
}

// ---------- line transpose role (6 blocks cover 3 lines x 512 pos) ----------
__device__ __forceinline__ void lines_role(int j, int t,
    const float* __restrict__ lz, const float* __restrict__ ly,
    const float* __restrict__ lx, char* __restrict__ ws)
{
    int id = j * 256 + t;
    int line = id >> 9;
    int pos = id & (RES - 1);
    const float* src = (line == 0) ? lz : ((line == 1) ? ly : lx);
    char* dst = ws + (size_t)3 * TEXELS * 96 + (size_t)line * RES * 96
                   + (size_t)pos * 96;
#pragma unroll
    for (int k = 0; k < 6; ++k) {
        uint4 q;
        q.x = pkbf(ntl(&src[(8 * k + 0) * RES + pos]), ntl(&src[(8 * k + 1) * RES + pos]));
        q.y = pkbf(ntl(&src[(8 * k + 2) * RES + pos]), ntl(&src[(8 * k + 3) * RES + pos]));
        q.z = pkbf(ntl(&src[(8 * k + 4) * RES + pos]), ntl(&src[(8 * k + 5) * RES + pos]));
        q.w = pkbf(ntl(&src[(8 * k + 6) * RES + pos]), ntl(&src[(8 * k + 7) * RES + pos]));
        *(uint4*)(dst + 16 * k) = q;
    }
}

// ---------- K1: lines || LDS-hist count || streaming tp ---------------------
// Count: segment s = blk, LDS histogram (4096 cells), coalesced dump to
// T[s][cell] (seg-major). Zero global atomics anywhere in the pipeline.
__global__ __launch_bounds__(256) void k1_prep(
    const float* __restrict__ coords, u32* __restrict__ T,
    const float* __restrict__ p0, const float* __restrict__ p1,
    const float* __restrict__ p2,
    const float* __restrict__ lz, const float* __restrict__ ly,
    const float* __restrict__ lx, char* __restrict__ ws)
{
    __shared__ u32 hist[NCELL];                     // 16 KB
    int bx = blockIdx.x, t = threadIdx.x;
    if (bx < LINB) {
        lines_role(bx, t, lz, ly, lx, ws);
    } else if (bx < LINB + NSEG) {
        int s = bx - LINB;
#pragma unroll
        for (int i = 0; i < NCELL / 256; ++i) hist[t + 256 * i] = 0u;
        __syncthreads();
        int base = s * SEGSZ;
        int lim = min(base + SEGSZ, NPTS);
#pragma unroll 1
        for (int idx = base + t; idx < lim; idx += 256) {
            float x = ntl(&coords[3 * idx + 0]);
            float y = ntl(&coords[3 * idx + 1]);
            float z = ntl(&coords[3 * idx + 2]);
            atomicAdd(&hist[cellOf(x, y, z)], 1u);  // LDS atomic only
        }
        __syncthreads();
        u32* Ts = T + (size_t)s * NCELL;
#pragma unroll
        for (int i = 0; i < NCELL / 256; ++i) {
            int cc = t + 256 * i;
            Ts[cc] = hist[cc];                      // coalesced 16KB dump
        }
    } else {
        tp_one4((bx - LINB - NSEG) * 256 + t, p0, p1, p2, ws);
    }
}

// ---------- K2a: per-cell prefix over segments (in place) -------------------
// thread <-> cell; loop over segs is lane-coalesced (seg-major T). 16 blocks.
__global__ __launch_bounds__(256) void k2_prefix(
    u32* __restrict__ T, u32* __restrict__ cellTot)
{
    int c = blockIdx.x * 256 + threadIdx.x;         // < 4096
    u32 run = 0;
#pragma unroll 8
    for (int s = 0; s < NSEG; ++s) {
        u32 v = T[(size_t)s * NCELL + c];
        T[(size_t)s * NCELL + c] = run;
        run += v;
    }
    cellTot[c] = run;
}

// ---------- K2b: exclusive scan of cellTot[4096] -> cellBase (1 block) ------
__global__ __launch_bounds__(256) void k2_base(
    const u32* __restrict__ cellTot, u32* __restrict__ cellBase)
{
    __shared__ u32 wt[4];
    int t = threadIdx.x;
    u32 loc[16];
    u32 s = 0;
#pragma unroll
    for (int i = 0; i < 16; ++i) { loc[i] = s; s += cellTot[t * 16 + i]; }
    u32 tot = s;
    int lane = t & 63, w = t >> 6;
    u32 incl = tot;
#pragma unroll
    for (int d = 1; d < 64; d <<= 1) {
        u32 v = __shfl_up(incl, d);
        if (lane >= d) incl += v;
    }
    if (lane == 63) wt[w] = incl;
    __syncthreads();
    u32 base = incl - tot;
#pragma unroll
    for (int i = 0; i < 4; ++i) base += (i < w) ? wt[i] : 0u;
#pragma unroll
    for (int i = 0; i < 16; ++i) cellBase[t * 16 + i] = base + loc[i];
}

// ---------- K3: scatter via LDS cursors (LDS atomics only) ------------------
__global__ __launch_bounds__(256) void k3_scatter(
    const float* __restrict__ coords, const u32* __restrict__ T,
    const u32* __restrict__ cellBase, vf4* __restrict__ rc2)
{
    __shared__ u32 cur[NCELL];                      // 16 KB cursors
    int s = blockIdx.x, t = threadIdx.x;
    const u32* Ts = T + (size_t)s * NCELL;
#pragma unroll
    for (int i = 0; i < NCELL / 256; ++i) {
        int cc = t + 256 * i;
        cur[cc] = cellBase[cc] + Ts[cc];            // coalesced
    }
    __syncthreads();
    int base = s * SEGSZ;
    int lim = min(base + SEGSZ, NPTS);
#pragma unroll 1
    for (int idx = base + t; idx < lim; idx += 256) {
        float x = ntl(&coords[3 * idx + 0]);
        float y = ntl(&coords[3 * idx + 1]);
        float z = ntl(&coords[3 * idx + 2]);
        u32 pos = atomicAdd(&cur[cellOf(x, y, z)], 1u);   // LDS atomic
        vf4 v; v.x = x; v.y = y; v.z = z; v.w = __uint_as_float((u32)idx);
        __builtin_nontemporal_store(v, rc2 + pos);
    }
}

// ---------- unsorted fallback transposes ------------------------------------
__global__ __launch_bounds__(256) void tp_stream_only(
    const float* __restrict__ p0, const float* __restrict__ p1,
    const float* __restrict__ p2, char* __restrict__ ws)
{
    tp_one4(blockIdx.x * 256 + threadIdx.x, p0, p1, p2, ws);   // grid = 768
}
__global__ __launch_bounds__(256) void lines_only(
    const float* __restrict__ lz, const float* __restrict__ ly,
    const float* __restrict__ lx, char* __restrict__ ws)
{
    lines_role(blockIdx.x, threadIdx.x, lz, ly, lx, ws);
}

// ---------- Pass 2: gather + interpolate (8 lanes/pt) + LDS + project -------
// Verbatim R6 (132 us, VGPR 36).
__device__ __forceinline__ void prep1(float g, int& i0, int& i1, float& w) {
    float p = fminf(fmaxf((g + 1.f) * 0.5f * 511.f, 0.f), 511.f);
    float fp = floorf(p);
    i0 = (int)fp;
    i1 = min(i0 + 1, RES - 1);
    w = p - fp;
}

// SORTED: cin = rc2 (vf4: x,y,z,bits(orig)); else cin = raw coords (float*3).
template <int TEXB, bool SORTED>
__global__ __launch_bounds__(512, 4) void geo_main(
    const void* __restrict__ cin, const char* __restrict__ ws,
    const float* __restrict__ W, const float* __restrict__ Bb,
    float* __restrict__ out)
{
    __shared__ float vm_lds[PPB * VMS];             // 13.3 KB (reused for staging)
    __shared__ u32 opt_lds[PPB];                    // orig point id per local point

    int tid = threadIdx.x;
    int ptL = tid >> 3;                             // 0..63
    int c = tid & 7;                                // chunk: ch 6c..6c+5

    int bid = blockIdx.x;
    if (SORTED) {
        // XCD-chunked bijective swizzle: consecutive Morton blocks share an XCD
        int nwg = gridDim.x;                        // 15625
        int q = nwg >> 3, r = nwg & 7;
        int xcd = bid & 7, slot = bid >> 3;
        bid = (xcd < r ? xcd * (q + 1) : r * (q + 1) + (xcd - r) * q) + slot;
    }
    int pt = bid * PPB + ptL;                       // NPTS = 15625*64 exactly

    float gx, gy, gz;
    if (SORTED) {
        vf4 cc = __builtin_nontemporal_load((const vf4*)cin + pt);
        gx = cc.x * 2.f - 1.f;
        gy = cc.y * 2.f - 1.f;
        gz = cc.z * 2.f - 1.f;
        if (c == 0) opt_lds[ptL] = __float_as_uint(cc.w);
    } else {
        const float* coords = (const float*)cin;
        gx = ntl(&coords[3 * pt + 0]) * 2.f - 1.f;
        gy = ntl(&coords[3 * pt + 1]) * 2.f - 1.f;
        gz = ntl(&coords[3 * pt + 2]) * 2.f - 1.f;
        if (c == 0) opt_lds[ptL] = (u32)pt;
    }

    int x0, x1, y0, y1, z0, z1;
    float wx, wy, wz;
    prep1(gx, x0, x1, wx);
    prep1(gy, y0, y1, wy);
    prep1(gz, z0, z1, wz);

    const size_t PW = (size_t)TEXELS * TEXB;
    const size_t LW = (size_t)RES * TEXB;
    const char* pxy = ws;
    const char* pxz = ws + PW;
    const char* pyz = ws + 2 * PW;
    const char* lzb = ws + 3 * PW;
    const char* lyb = lzb + LW;
    const char* lxb = lyb + LW;

    u32 co = 12u * (u32)c;                          // byte offset of chunk in texel

    u32 q[12][3], le[3][3], lf[3][3];
    {
        u32 offs[12];
        offs[0] = (u32)(y0 * RES + x0) * TEXB + co;
        offs[1] = (u32)(y0 * RES + x1) * TEXB + co;
        offs[2] = (u32)(y1 * RES + x0) * TEXB + co;
        offs[3] = (u32)(y1 * RES + x1) * TEXB + co;
        offs[4] = (u32)(z0 * RES + x0) * TEXB + co;
        offs[5] = (u32)(z0 * RES + x1) * TEXB + co;
        offs[6] = (u32)(z1 * RES + x0) * TEXB + co;
        offs[7] = (u32)(z1 * RES + x1) * TEXB + co;
        offs[8]  = (u32)(z0 * RES + y0) * TEXB + co;
        offs[9]  = (u32)(z0 * RES + y1) * TEXB + co;
        offs[10] = (u32)(z1 * RES + y0) * TEXB + co;
        offs[11] = (u32)(z1 * RES + y1) * TEXB + co;
        const char* bases[3] = { pxy, pxz, pyz };
#pragma unroll
        for (int p = 0; p < 3; ++p) {
#pragma unroll
            for (int k = 0; k < 4; ++k) {
                const u32* s = (const u32*)(bases[p] + offs[4 * p + k]);
                q[4 * p + k][0] = s[0];
                q[4 * p + k][1] = s[1];
                q[4 * p + k][2] = s[2];
            }
        }
        const char* lb[3] = { lzb, lyb, lxb };
        u32 l0[3] = { (u32)z0 * TEXB + co, (u32)y0 * TEXB + co, (u32)x0 * TEXB + co };
        u32 l1[3] = { (u32)z1 * TEXB + co, (u32)y1 * TEXB + co, (u32)x1 * TEXB + co };
#pragma unroll
        for (int p = 0; p < 3; ++p) {
            const u32* s0 = (const u32*)(lb[p] + l0[p]);
            const u32* s1 = (const u32*)(lb[p] + l1[p]);
            le[p][0] = s0[0]; le[p][1] = s0[1]; le[p][2] = s0[2];
            lf[p][0] = s1[0]; lf[p][1] = s1[1]; lf[p][2] = s1[2];
        }
    }

    float pw[3][4];
    pw[0][0] = (1.f - wy) * (1.f - wx); pw[0][1] = (1.f - wy) * wx;
    pw[0][2] = wy * (1.f - wx);         pw[0][3] = wy * wx;
    pw[1][0] = (1.f - wz) * (1.f - wx); pw[1][1] = (1.f - wz) * wx;
    pw[1][2] = wz * (1.f - wx);         pw[1][3] = wz * wx;
    pw[2][0] = (1.f - wz) * (1.f - wy); pw[2][1] = (1.f - wz) * wy;
    pw[2][2] = wz * (1.f - wy);         pw[2][3] = wz * wy;
    float lw[3] = { wz, wy, wx };

    float vm[6] = { 0.f, 0.f, 0.f, 0.f, 0.f, 0.f };
#pragma unroll
    for (int p = 0; p < 3; ++p) {
        float s0 = pw[p][0], s1 = pw[p][1], s2 = pw[p][2], s3 = pw[p][3];
        float il = 1.f - lw[p], wl = lw[p];
#pragma unroll
        for (int d = 0; d < 3; ++d) {               // dword d -> ch 2d, 2d+1
            u32 a = q[4 * p + 0][d], b = q[4 * p + 1][d];
            u32 cc = q[4 * p + 2][d], dd = q[4 * p + 3][d];
            float slo = s0 * lobf(a) + s1 * lobf(b) + s2 * lobf(cc) + s3 * lobf(dd);
            float shi = s0 * hibf(a) + s1 * hibf(b) + s2 * hibf(cc) + s3 * hibf(dd);
            float llo = il * lobf(le[p][d]) + wl * lobf(lf[p][d]);
            float lhi = il * hibf(le[p][d]) + wl * hibf(lf[p][d]);
            vm[2 * d + 0] = fmaf(slo, llo, vm[2 * d + 0]);
            vm[2 * d + 1] = fmaf(shi, lhi, vm[2 * d + 1]);
        }
    }

    float* vr = vm_lds + ptL * VMS + 6 * c;
    *(float2*)(vr + 0) = make_float2(vm[0], vm[1]);
    *(float2*)(vr + 2) = make_float2(vm[2], vm[3]);
    *(float2*)(vr + 4) = make_float2(vm[4], vm[5]);

    __syncthreads();

    int wav = __builtin_amdgcn_readfirstlane(tid >> 6);   // 0..7, wave-uniform
    int lane = tid & 63;                                  // local point
    int ob = wav * 4;

    const float* vmrow = vm_lds + lane * VMS;
    float4 bb = *(const float4*)(Bb + ob);                // uniform -> s_load
    float a0 = bb.x, a1 = bb.y, a2 = bb.z, a3 = bb.w;
#pragma unroll 4
    for (int k = 0; k < 12; ++k) {
        float4 v = *(const float4*)(vmrow + 4 * k);       // ds_read_b128
        float4 w0 = *(const float4*)(W + (ob + 0) * RANK + 4 * k);  // s_loads
        float4 w1 = *(const float4*)(W + (ob + 1) * RANK + 4 * k);
        float4 w2 = *(const float4*)(W + (ob + 2) * RANK + 4 * k);
        float4 w3 = *(const float4*)(W + (ob + 3) * RANK + 4 * k);
        a0 = fmaf(v.x, w0.x, a0); a0 = fmaf(v.y, w0.y, a0);
        a0 = fmaf(v.z, w0.z, a0); a0 = fmaf(v.w, w0.w, a0);
        a1 = fmaf(v.x, w1.x, a1); a1 = fmaf(v.y, w1.y, a1);
        a1 = fmaf(v.z, w1.z, a1); a1 = fmaf(v.w, w1.w, a1);
        a2 = fmaf(v.x, w2.x, a2); a2 = fmaf(v.y, w2.y, a2);
        a2 = fmaf(v.z, w2.z, a2); a2 = fmaf(v.w, w2.w, a2);
        a3 = fmaf(v.x, w3.x, a3); a3 = fmaf(v.y, w3.y, a3);
        a3 = fmaf(v.z, w3.z, a3); a3 = fmaf(v.w, w3.w, a3);
    }

    // ---- output staging: full 128B rows per wave; rows scattered by orig id
    __syncthreads();
    {
        vf4 r; r.x = a0; r.y = a1; r.z = a2; r.w = a3;
        *(vf4*)(vm_lds + lane * OSTR + ob) = r;
    }
    __syncthreads();
    {
        int p8 = lane >> 3;
        int c2 = lane & 7;
        int gp = wav * 8 + p8;
        vf4 v = *(const vf4*)(vm_lds + gp * OSTR + 4 * c2);
        size_t orow = (size_t)opt_lds[gp];
        __builtin_nontemporal_store(v, (vf4*)(out + orow * ODIM + 4 * c2));
    }
}

// ---------- Launch ----------------------------------------------------------
extern "C" void kernel_launch(void* const* d_in, const int* in_sizes, int n_in,
                              void* d_out, int out_size, void* d_ws, size_t ws_size,
                              hipStream_t stream) {
    const float* coords = (const float*)d_in[0];
    const float* pxy = (const float*)d_in[1];
    const float* pxz = (const float*)d_in[2];
    const float* pyz = (const float*)d_in[3];
    const float* lz = (const float*)d_in[4];
    const float* ly = (const float*)d_in[5];
    const float* lx = (const float*)d_in[6];
    const float* W = (const float*)d_in[7];
    const float* Bb = (const float*)d_in[8];
    float* out = (float*)d_out;
    char* ws = (char*)d_ws;

    size_t pool96 = (size_t)3 * TEXELS * 96 + (size_t)3 * RES * 96;   // 75,644,928
    size_t o_T = (pool96 + 255) & ~(size_t)255;
    size_t o_ct = o_T + (size_t)NSEG * NCELL * 4;   // T: 4 MB
    size_t o_cb = o_ct + (size_t)NCELL * 4;         // cellTot: 16 KB
    size_t o_rc2 = o_cb + (size_t)NCELL * 4;        // cellBase: 16 KB
    size_t need_sorted = o_rc2 + (size_t)NPTS * 16; // ~95.9 MB (< 100.8 proven)

    if (ws_size >= need_sorted) {
        u32* T = (u32*)(ws + o_T);
        u32* cellTot = (u32*)(ws + o_ct);
        u32* cellBase = (u32*)(ws + o_cb);
        vf4* rc2 = (vf4*)(ws + o_rc2);

        k1_prep<<<LINB + NSEG + TPB4, 256, 0, stream>>>(coords, T,
                                                        pxy, pxz, pyz,
                                                        lz, ly, lx, ws);
        k2_prefix<<<NCELL / 256, 256, 0, stream>>>(T, cellTot);
        k2_base<<<1, 256, 0, stream>>>(cellTot, cellBase);
        k3_scatter<<<NSEG, 256, 0, stream>>>(coords, T, cellBase, rc2);
        geo_main<96, true><<<NPTS / PPB, 512, 0, stream>>>(rc2, ws, W, Bb, out);
    } else {
        // unsorted fallback (small workspace): streaming tp + lines + geo
        tp_stream_only<<<TPB4, 256, 0, stream>>>(pxy, pxz, pyz, ws);
        lines_only<<<6, 256, 0, stream>>>(lz, ly, lx, ws);
        geo_main<96, false><<<NPTS / PPB, 512, 0, stream>>>(coords, ws, W, Bb, out);
    }
}